// Round 1
// baseline (1466.611 us; speedup 1.0000x reference)
//
#include <hip/hip_runtime.h>

#define N_NODES 100000
#define N_EDGES 1250000
#define HID 64
#define N_GRAPHS 512
#define OUT_CH 16

// ---------------------------------------------------------------------------
// Kernel 1: H = relu(X @ W + b); Z = H  (Z becomes the h+agg accumulator)
// One wave per row; lane = output channel; W staged in LDS (conflict-free:
// lane c hits bank c%32, 2-way aliasing across half-waves is free).
// ---------------------------------------------------------------------------
__global__ __launch_bounds__(256) void k_lin0(const float* __restrict__ X,
                                              const float* __restrict__ W,
                                              const float* __restrict__ B,
                                              float* __restrict__ H,
                                              float* __restrict__ Z) {
    __shared__ float sW[HID * HID];
    __shared__ float sB[HID];
    int tid = threadIdx.x;
#pragma unroll
    for (int i = 0; i < 16; ++i) sW[tid + 256 * i] = W[tid + 256 * i];
    if (tid < HID) sB[tid] = B[tid];
    __syncthreads();

    int lane   = tid & 63;
    int gwave  = (blockIdx.x * 256 + tid) >> 6;
    int nwaves = (gridDim.x * 256) >> 6;
    for (int row = gwave; row < N_NODES; row += nwaves) {
        float xv  = X[row * HID + lane];
        float acc = sB[lane];
#pragma unroll
        for (int k = 0; k < HID; ++k) {
            acc += __shfl(xv, k, 64) * sW[k * HID + lane];
        }
        acc = fmaxf(acc, 0.0f);
        H[row * HID + lane] = acc;
        Z[row * HID + lane] = acc;
    }
}

// ---------------------------------------------------------------------------
// Scatter-add: Z[dst] += H[src] for every edge. One wave per edge, lane =
// channel: src/dst loads are wave-broadcast, H gather is one coalesced 256B
// row read, atomics land on 64 consecutive addresses.
// ---------------------------------------------------------------------------
__global__ __launch_bounds__(256) void k_scatter(const int* __restrict__ src,
                                                 const int* __restrict__ dst,
                                                 const float* __restrict__ H,
                                                 float* __restrict__ Z) {
    int lane       = threadIdx.x & 63;
    int gwave      = (blockIdx.x * 256 + threadIdx.x) >> 6;
    int wavesTotal = (gridDim.x * 256) >> 6;
    for (int e = gwave; e < N_EDGES; e += wavesTotal) {
        int s = src[e];
        int d = dst[e];
        float v = H[(long long)s * HID + lane];
        atomicAdd(&Z[(long long)d * HID + lane], v);
    }
}

// ---------------------------------------------------------------------------
// Fused GIN MLP: h_new = relu( relu(Z@Wa+ba) @ Wb + bb ).
// Writes h_new to H and re-initializes Z = h_new for the next layer's
// scatter accumulation. Both weights staged in LDS (32 KB/block).
// ---------------------------------------------------------------------------
__global__ __launch_bounds__(256) void k_mlp(const float* __restrict__ Wa,
                                             const float* __restrict__ Ba,
                                             const float* __restrict__ Wb,
                                             const float* __restrict__ Bb,
                                             float* __restrict__ Z,
                                             float* __restrict__ H) {
    __shared__ float sWa[HID * HID];
    __shared__ float sWb[HID * HID];
    __shared__ float sBa[HID];
    __shared__ float sBb[HID];
    int tid = threadIdx.x;
#pragma unroll
    for (int i = 0; i < 16; ++i) {
        sWa[tid + 256 * i] = Wa[tid + 256 * i];
        sWb[tid + 256 * i] = Wb[tid + 256 * i];
    }
    if (tid < HID) { sBa[tid] = Ba[tid]; sBb[tid] = Bb[tid]; }
    __syncthreads();

    int lane   = tid & 63;
    int gwave  = (blockIdx.x * 256 + tid) >> 6;
    int nwaves = (gridDim.x * 256) >> 6;
    for (int row = gwave; row < N_NODES; row += nwaves) {
        float zv   = Z[row * HID + lane];
        float acc1 = sBa[lane];
#pragma unroll
        for (int k = 0; k < HID; ++k) {
            acc1 += __shfl(zv, k, 64) * sWa[k * HID + lane];
        }
        float t    = fmaxf(acc1, 0.0f);
        float acc2 = sBb[lane];
#pragma unroll
        for (int k = 0; k < HID; ++k) {
            acc2 += __shfl(t, k, 64) * sWb[k * HID + lane];
        }
        float h = fmaxf(acc2, 0.0f);
        H[row * HID + lane] = h;
        Z[row * HID + lane] = h;
    }
}

// ---------------------------------------------------------------------------
// Layer-3 MLP fused with global mean-pool accumulation (sums + counts).
// ---------------------------------------------------------------------------
__global__ __launch_bounds__(256) void k_mlp_pool(const float* __restrict__ Wa,
                                                  const float* __restrict__ Ba,
                                                  const float* __restrict__ Wb,
                                                  const float* __restrict__ Bb,
                                                  const float* __restrict__ Z,
                                                  const int* __restrict__ batch,
                                                  float* __restrict__ pool,
                                                  float* __restrict__ cnt) {
    __shared__ float sWa[HID * HID];
    __shared__ float sWb[HID * HID];
    __shared__ float sBa[HID];
    __shared__ float sBb[HID];
    int tid = threadIdx.x;
#pragma unroll
    for (int i = 0; i < 16; ++i) {
        sWa[tid + 256 * i] = Wa[tid + 256 * i];
        sWb[tid + 256 * i] = Wb[tid + 256 * i];
    }
    if (tid < HID) { sBa[tid] = Ba[tid]; sBb[tid] = Bb[tid]; }
    __syncthreads();

    int lane   = tid & 63;
    int gwave  = (blockIdx.x * 256 + tid) >> 6;
    int nwaves = (gridDim.x * 256) >> 6;
    for (int row = gwave; row < N_NODES; row += nwaves) {
        float zv   = Z[row * HID + lane];
        float acc1 = sBa[lane];
#pragma unroll
        for (int k = 0; k < HID; ++k) {
            acc1 += __shfl(zv, k, 64) * sWa[k * HID + lane];
        }
        float t    = fmaxf(acc1, 0.0f);
        float acc2 = sBb[lane];
#pragma unroll
        for (int k = 0; k < HID; ++k) {
            acc2 += __shfl(t, k, 64) * sWb[k * HID + lane];
        }
        float h = fmaxf(acc2, 0.0f);
        int g = batch[row];
        atomicAdd(&pool[g * HID + lane], h);
        if (lane == 0) atomicAdd(&cnt[g], 1.0f);
    }
}

// ---------------------------------------------------------------------------
// Readout: out[g] = (pool[g]/max(cnt[g],1)) @ Wl + bl.  512 blocks x 64.
// ---------------------------------------------------------------------------
__global__ __launch_bounds__(64) void k_final(const float* __restrict__ pool,
                                              const float* __restrict__ cnt,
                                              const float* __restrict__ Wl,
                                              const float* __restrict__ bl,
                                              float* __restrict__ out) {
    __shared__ float sp[HID];
    int g    = blockIdx.x;
    int lane = threadIdx.x;
    float c  = fmaxf(cnt[g], 1.0f);
    sp[lane] = pool[g * HID + lane] / c;
    __syncthreads();
    if (lane < OUT_CH) {
        float acc = bl[lane];
#pragma unroll
        for (int k = 0; k < HID; ++k) acc += sp[k] * Wl[k * OUT_CH + lane];
        out[g * OUT_CH + lane] = acc;
    }
}

extern "C" void kernel_launch(void* const* d_in, const int* in_sizes, int n_in,
                              void* d_out, int out_size, void* d_ws, size_t ws_size,
                              hipStream_t stream) {
    const float* x     = (const float*)d_in[0];
    const int*   edge  = (const int*)d_in[1];   // [2][N_EDGES], int32
    const int*   batch = (const int*)d_in[2];   // [N_NODES], int32
    const float* W0  = (const float*)d_in[3];
    const float* b0  = (const float*)d_in[4];
    const float* W1a = (const float*)d_in[5];
    const float* b1a = (const float*)d_in[6];
    const float* W1b = (const float*)d_in[7];
    const float* b1b = (const float*)d_in[8];
    const float* W2a = (const float*)d_in[9];
    const float* b2a = (const float*)d_in[10];
    const float* W2b = (const float*)d_in[11];
    const float* b2b = (const float*)d_in[12];
    const float* W3a = (const float*)d_in[13];
    const float* b3a = (const float*)d_in[14];
    const float* W3b = (const float*)d_in[15];
    const float* b3b = (const float*)d_in[16];
    const float* Wl  = (const float*)d_in[17];
    const float* bl  = (const float*)d_in[18];

    float* out = (float*)d_out;  // [N_GRAPHS, OUT_CH] fp32

    // Workspace layout (fp32): H [N,64] | Z [N,64] | pool [G,64] | cnt [G]
    float* H    = (float*)d_ws;
    float* Z    = H + (size_t)N_NODES * HID;
    float* pool = Z + (size_t)N_NODES * HID;
    float* cnt  = pool + (size_t)N_GRAPHS * HID;

    const int* src = edge;
    const int* dst = edge + N_EDGES;

    // Zero pooling accumulators (ws is re-poisoned to 0xAA before each call).
    hipMemsetAsync(pool, 0, (size_t)(N_GRAPHS * HID + N_GRAPHS) * sizeof(float), stream);

    // Input linear (+relu), initializes Z = h0.
    k_lin0<<<1024, 256, 0, stream>>>(x, W0, b0, H, Z);

    // Layer 1
    k_scatter<<<8192, 256, 0, stream>>>(src, dst, H, Z);
    k_mlp<<<1024, 256, 0, stream>>>(W1a, b1a, W1b, b1b, Z, H);

    // Layer 2
    k_scatter<<<8192, 256, 0, stream>>>(src, dst, H, Z);
    k_mlp<<<1024, 256, 0, stream>>>(W2a, b2a, W2b, b2b, Z, H);

    // Layer 3 (+ fused mean-pool accumulation)
    k_scatter<<<8192, 256, 0, stream>>>(src, dst, H, Z);
    k_mlp_pool<<<1024, 256, 0, stream>>>(W3a, b3a, W3b, b3b, Z, batch, pool, cnt);

    // Readout
    k_final<<<N_GRAPHS, 64, 0, stream>>>(pool, cnt, Wl, bl, out);
}

// Round 2
// 609.043 us; speedup vs baseline: 2.4081x; 2.4081x over previous
//
#include <hip/hip_runtime.h>

#define N_NODES 100000
#define N_EDGES 1250000
#define HID 64
#define N_GRAPHS 512
#define OUT_CH 16
#define CHUNK 2048
#define NCHUNK ((N_NODES + CHUNK - 1) / CHUNK)  // 49

// ===========================================================================
// CSR build: deg histogram -> 2-level exclusive scan -> fill (sort-by-dst)
// ===========================================================================
__global__ void k_hist(const int* __restrict__ dst, int* __restrict__ deg) {
    int i = blockIdx.x * blockDim.x + threadIdx.x;
    int stride = gridDim.x * blockDim.x;
    for (; i < N_EDGES; i += stride) atomicAdd(&deg[dst[i]], 1);
}

__global__ __launch_bounds__(256) void k_chunksum(const int* __restrict__ deg,
                                                  int* __restrict__ chunkSum) {
    __shared__ int s[256];
    int c = blockIdx.x, t = threadIdx.x;
    int base = c * CHUNK;
    int sum = 0;
    for (int i = t; i < CHUNK; i += 256) {
        int idx = base + i;
        if (idx < N_NODES) sum += deg[idx];
    }
    s[t] = sum;
    __syncthreads();
    for (int off = 128; off > 0; off >>= 1) {
        if (t < off) s[t] += s[t + off];
        __syncthreads();
    }
    if (t == 0) chunkSum[c] = s[0];
}

__global__ __launch_bounds__(64) void k_scanchunks(const int* __restrict__ chunkSum,
                                                   int* __restrict__ chunkOff,
                                                   int* __restrict__ rowptr) {
    int t = threadIdx.x;
    int v = (t < NCHUNK) ? chunkSum[t] : 0;
    int orig = v;
    for (int off = 1; off < 64; off <<= 1) {
        int u = __shfl_up(v, off, 64);
        if (t >= off) v += u;
    }
    if (t < NCHUNK) chunkOff[t] = v - orig;   // exclusive
    if (t == 0) rowptr[N_NODES] = N_EDGES;
}

__global__ __launch_bounds__(256) void k_scanwrite(const int* __restrict__ deg,
                                                   const int* __restrict__ chunkOff,
                                                   int* __restrict__ rowptr) {
    __shared__ int s[256];
    int c = blockIdx.x, t = threadIdx.x;
    int base = c * CHUNK + t * 8;
    int v[8];
    int tot = 0;
#pragma unroll
    for (int i = 0; i < 8; ++i) {
        int idx = base + i;
        v[i] = (idx < N_NODES) ? deg[idx] : 0;
        tot += v[i];
    }
    s[t] = tot;
    __syncthreads();
    for (int off = 1; off < 256; off <<= 1) {
        int u = (t >= off) ? s[t - off] : 0;
        __syncthreads();
        s[t] += u;
        __syncthreads();
    }
    int pref = chunkOff[c] + s[t] - tot;  // exclusive prefix for this thread
#pragma unroll
    for (int i = 0; i < 8; ++i) {
        int idx = base + i;
        if (idx < N_NODES) rowptr[idx] = pref;
        pref += v[i];
    }
}

__global__ void k_fill(const int* __restrict__ src, const int* __restrict__ dst,
                       int* __restrict__ cursor, int* __restrict__ csrSrc) {
    int i = blockIdx.x * blockDim.x + threadIdx.x;
    int stride = gridDim.x * blockDim.x;
    for (; i < N_EDGES; i += stride) {
        int d = dst[i];
        int pos = atomicAdd(&cursor[d], 1);
        csrSrc[pos] = src[i];
    }
}

// ===========================================================================
// Aggregate (no atomics): Z[i] = H[i] + sum_{j in in(i)} H[src_j]
// Wave per node, lane = channel; register accumulation; 4-way index unroll.
// ===========================================================================
__global__ __launch_bounds__(256) void k_aggregate(const int* __restrict__ rowptr,
                                                   const int* __restrict__ csrSrc,
                                                   const float* __restrict__ H,
                                                   float* __restrict__ Z) {
    int lane = threadIdx.x & 63;
    int gwave = (blockIdx.x * 256 + threadIdx.x) >> 6;
    int nw = (gridDim.x * 256) >> 6;
    for (int i = gwave; i < N_NODES; i += nw) {
        int start = rowptr[i], end = rowptr[i + 1];
        float z = H[(size_t)i * HID + lane];
        int j = start;
        for (; j + 4 <= end; j += 4) {
            int s0 = csrSrc[j], s1 = csrSrc[j + 1], s2 = csrSrc[j + 2], s3 = csrSrc[j + 3];
            float v0 = H[(size_t)s0 * HID + lane];
            float v1 = H[(size_t)s1 * HID + lane];
            float v2 = H[(size_t)s2 * HID + lane];
            float v3 = H[(size_t)s3 * HID + lane];
            z += v0; z += v1; z += v2; z += v3;
        }
        for (; j < end; ++j) z += H[(size_t)csrSrc[j] * HID + lane];
        Z[(size_t)i * HID + lane] = z;
    }
}

// ===========================================================================
// Tiled register-blocked GEMM pieces.
// Tile: 64 rows x 64 cols per block of 256 threads; thread = 4 rows x 4 cols.
// A staged TRANSPOSED in LDS (sA[k][row], stride 64) so the per-k A fragment
// is one ds_read_b128; W staged as [k][col] so B fragment is one b128
// (same-address broadcast across the 16 lanes sharing a tc).
// ===========================================================================
__device__ __forceinline__ void stage_rows_T(const float* __restrict__ G, int row0,
                                             float* sA, int t) {
    int rowL = t >> 2;  // 0..63
    int seg = t & 3;    // 0..3
    int grow = row0 + rowL;
#pragma unroll
    for (int q = 0; q < 4; ++q) {
        int k0 = seg * 16 + q * 4;
        float4 v = (grow < N_NODES) ? *(const float4*)&G[(size_t)grow * HID + k0]
                                    : make_float4(0.f, 0.f, 0.f, 0.f);
        sA[(k0 + 0) * HID + rowL] = v.x;
        sA[(k0 + 1) * HID + rowL] = v.y;
        sA[(k0 + 2) * HID + rowL] = v.z;
        sA[(k0 + 3) * HID + rowL] = v.w;
    }
}

// One 64x64 matmul from transposed-A LDS + W LDS; acc[i][j] pre-initialized.
__device__ __forceinline__ void mm64(const float* sA, const float* sW, int tr, int tc,
                                     float acc[4][4]) {
#pragma unroll 8
    for (int k = 0; k < HID; ++k) {
        float4 a = *(const float4*)&sA[k * HID + 4 * tr];
        float4 b = *(const float4*)&sW[k * HID + 4 * tc];
        const float av[4] = {a.x, a.y, a.z, a.w};
        const float bv[4] = {b.x, b.y, b.z, b.w};
#pragma unroll
        for (int i = 0; i < 4; ++i)
#pragma unroll
            for (int j = 0; j < 4; ++j) acc[i][j] = fmaf(av[i], bv[j], acc[i][j]);
    }
}

// h = relu(X @ W + b) -> Hout
__global__ __launch_bounds__(256) void k_lin(const float* __restrict__ W,
                                             const float* __restrict__ B,
                                             const float* __restrict__ Xin,
                                             float* __restrict__ Hout) {
    __shared__ float sA[HID * HID];
    __shared__ float sW[HID * HID];
    int t = threadIdx.x;
    int row0 = blockIdx.x * 64;
#pragma unroll
    for (int i = 0; i < 16; ++i) sW[t + 256 * i] = W[t + 256 * i];
    stage_rows_T(Xin, row0, sA, t);
    __syncthreads();

    int tr = t & 15, tc = t >> 4;
    float4 b4 = *(const float4*)&B[4 * tc];
    float acc[4][4];
#pragma unroll
    for (int i = 0; i < 4; ++i) {
        acc[i][0] = b4.x; acc[i][1] = b4.y; acc[i][2] = b4.z; acc[i][3] = b4.w;
    }
    mm64(sA, sW, tr, tc, acc);
#pragma unroll
    for (int i = 0; i < 4; ++i) {
        int row = row0 + 4 * tr + i;
        if (row < N_NODES) {
            float4 o = make_float4(fmaxf(acc[i][0], 0.f), fmaxf(acc[i][1], 0.f),
                                   fmaxf(acc[i][2], 0.f), fmaxf(acc[i][3], 0.f));
            *(float4*)&Hout[(size_t)row * HID + 4 * tc] = o;
        }
    }
}

// H = relu( relu(Z@Wa+ba) @ Wb + bb )
__global__ __launch_bounds__(256) void k_mlp(const float* __restrict__ Wa,
                                             const float* __restrict__ Ba,
                                             const float* __restrict__ Wb,
                                             const float* __restrict__ Bb,
                                             const float* __restrict__ Zin,
                                             float* __restrict__ Hout) {
    __shared__ float sA[HID * HID];
    __shared__ float sWa[HID * HID];
    __shared__ float sWb[HID * HID];
    int t = threadIdx.x;
    int row0 = blockIdx.x * 64;
#pragma unroll
    for (int i = 0; i < 16; ++i) {
        sWa[t + 256 * i] = Wa[t + 256 * i];
        sWb[t + 256 * i] = Wb[t + 256 * i];
    }
    stage_rows_T(Zin, row0, sA, t);
    __syncthreads();

    int tr = t & 15, tc = t >> 4;
    float4 ba = *(const float4*)&Ba[4 * tc];
    float4 bb = *(const float4*)&Bb[4 * tc];
    float acc[4][4];
#pragma unroll
    for (int i = 0; i < 4; ++i) {
        acc[i][0] = ba.x; acc[i][1] = ba.y; acc[i][2] = ba.z; acc[i][3] = ba.w;
    }
    mm64(sA, sWa, tr, tc, acc);

    __syncthreads();  // all loop-1 reads of sA done
    // write T = relu(.) transposed back into sA: sA[mid][row]
#pragma unroll
    for (int i = 0; i < 4; ++i)
#pragma unroll
        for (int j = 0; j < 4; ++j)
            sA[(4 * tc + j) * HID + (4 * tr + i)] = fmaxf(acc[i][j], 0.f);
    __syncthreads();

#pragma unroll
    for (int i = 0; i < 4; ++i) {
        acc[i][0] = bb.x; acc[i][1] = bb.y; acc[i][2] = bb.z; acc[i][3] = bb.w;
    }
    mm64(sA, sWb, tr, tc, acc);

#pragma unroll
    for (int i = 0; i < 4; ++i) {
        int row = row0 + 4 * tr + i;
        if (row < N_NODES) {
            float4 o = make_float4(fmaxf(acc[i][0], 0.f), fmaxf(acc[i][1], 0.f),
                                   fmaxf(acc[i][2], 0.f), fmaxf(acc[i][3], 0.f));
            *(float4*)&Hout[(size_t)row * HID + 4 * tc] = o;
        }
    }
}

// ===========================================================================
// Pool: batch is sorted; one wave per graph, binary-search the segment,
// stream-sum rows, divide by count. No atomics.
// ===========================================================================
__global__ __launch_bounds__(256) void k_pool(const float* __restrict__ H,
                                              const int* __restrict__ batch,
                                              float* __restrict__ pooled) {
    int lane = threadIdx.x & 63;
    int g = (blockIdx.x * 256 + threadIdx.x) >> 6;
    if (g >= N_GRAPHS) return;
    int lo = 0, hi = N_NODES;
    while (lo < hi) { int m = (lo + hi) >> 1; if (batch[m] < g) lo = m + 1; else hi = m; }
    int start = lo;
    hi = N_NODES;
    while (lo < hi) { int m = (lo + hi) >> 1; if (batch[m] < g + 1) lo = m + 1; else hi = m; }
    int end = lo;
    float s = 0.f;
    for (int r = start; r < end; ++r) s += H[(size_t)r * HID + lane];
    float c = (end > start) ? (float)(end - start) : 1.0f;
    pooled[g * HID + lane] = s / c;
}

__global__ __launch_bounds__(64) void k_final(const float* __restrict__ pooled,
                                              const float* __restrict__ Wl,
                                              const float* __restrict__ bl,
                                              float* __restrict__ out) {
    __shared__ float sp[HID];
    int g = blockIdx.x, lane = threadIdx.x;
    sp[lane] = pooled[g * HID + lane];
    __syncthreads();
    if (lane < OUT_CH) {
        float acc = bl[lane];
#pragma unroll
        for (int k = 0; k < HID; ++k) acc += sp[k] * Wl[k * OUT_CH + lane];
        out[g * OUT_CH + lane] = acc;
    }
}

extern "C" void kernel_launch(void* const* d_in, const int* in_sizes, int n_in,
                              void* d_out, int out_size, void* d_ws, size_t ws_size,
                              hipStream_t stream) {
    const float* x     = (const float*)d_in[0];
    const int*   edge  = (const int*)d_in[1];   // [2][N_EDGES] int32
    const int*   batch = (const int*)d_in[2];   // [N_NODES] int32 (sorted)
    const float* W0  = (const float*)d_in[3];
    const float* b0  = (const float*)d_in[4];
    const float* W1a = (const float*)d_in[5];
    const float* b1a = (const float*)d_in[6];
    const float* W1b = (const float*)d_in[7];
    const float* b1b = (const float*)d_in[8];
    const float* W2a = (const float*)d_in[9];
    const float* b2a = (const float*)d_in[10];
    const float* W2b = (const float*)d_in[11];
    const float* b2b = (const float*)d_in[12];
    const float* W3a = (const float*)d_in[13];
    const float* b3a = (const float*)d_in[14];
    const float* W3b = (const float*)d_in[15];
    const float* b3b = (const float*)d_in[16];
    const float* Wl  = (const float*)d_in[17];
    const float* bl  = (const float*)d_in[18];
    float* out = (float*)d_out;

    const int* src = edge;
    const int* dst = edge + N_EDGES;

    // Workspace layout
    float* H      = (float*)d_ws;                         // [N,64]
    float* Z      = H + (size_t)N_NODES * HID;            // [N,64]
    float* pooled = Z + (size_t)N_NODES * HID;            // [G,64]
    int*   deg      = (int*)(pooled + (size_t)N_GRAPHS * HID);  // [N]
    int*   rowptr   = deg + N_NODES;                      // [N+1]
    int*   cursor   = rowptr + N_NODES + 1;               // [N]
    int*   chunkSum = cursor + N_NODES;                   // [NCHUNK]
    int*   chunkOff = chunkSum + NCHUNK;                  // [NCHUNK]
    int*   csrSrc   = chunkOff + NCHUNK;                  // [E]

    const int MLP_BLOCKS = (N_NODES + 63) / 64;           // 1563

    // ---- CSR build (amortized over 3 layers) ----
    hipMemsetAsync(deg, 0, N_NODES * sizeof(int), stream);
    k_hist<<<2048, 256, 0, stream>>>(dst, deg);
    k_chunksum<<<NCHUNK, 256, 0, stream>>>(deg, chunkSum);
    k_scanchunks<<<1, 64, 0, stream>>>(chunkSum, chunkOff, rowptr);
    k_scanwrite<<<NCHUNK, 256, 0, stream>>>(deg, chunkOff, rowptr);
    hipMemcpyAsync(cursor, rowptr, N_NODES * sizeof(int), hipMemcpyDeviceToDevice, stream);
    k_fill<<<2048, 256, 0, stream>>>(src, dst, cursor, csrSrc);

    // ---- Input linear ----
    k_lin<<<MLP_BLOCKS, 256, 0, stream>>>(W0, b0, x, H);

    // ---- 3 GIN layers: aggregate (Z = H + sum H[src]) then MLP (H = mlp(Z)) ----
    k_aggregate<<<2048, 256, 0, stream>>>(rowptr, csrSrc, H, Z);
    k_mlp<<<MLP_BLOCKS, 256, 0, stream>>>(W1a, b1a, W1b, b1b, Z, H);

    k_aggregate<<<2048, 256, 0, stream>>>(rowptr, csrSrc, H, Z);
    k_mlp<<<MLP_BLOCKS, 256, 0, stream>>>(W2a, b2a, W2b, b2b, Z, H);

    k_aggregate<<<2048, 256, 0, stream>>>(rowptr, csrSrc, H, Z);
    k_mlp<<<MLP_BLOCKS, 256, 0, stream>>>(W3a, b3a, W3b, b3b, Z, H);

    // ---- Readout ----
    k_pool<<<(N_GRAPHS * 64 + 255) / 256, 256, 0, stream>>>(H, batch, pooled);
    k_final<<<N_GRAPHS, 64, 0, stream>>>(pooled, Wl, bl, out);
}